// Round 8
// baseline (204.496 us; speedup 1.0000x reference)
//
#include <hip/hip_runtime.h>
#include <stdint.h>
#include <stddef.h>

// CliffordLinear as one bf16 GEMM:
//   out[b, o*8+l] = sum_{i,k} X[b, i*8+k] * Wt[o*8+l, i*8+k] + bias[o*8+l]
//   Wt[(o,l),(i,k)] = sum_j cayley[j,k,l] * W[o,i,j]
// M=8192, N=2048, K=2048. bf16 MFMA, fp32 accumulate.
//
// R8: AITER-style hybrid K-loop. A stays on the verified R7 path
// (global_load_lds width-16 -> LDS dbuf, XOR source swizzle, 0 conflicts).
// B bypasses LDS entirely: prep writes Wt in FRAG-MAJOR layout so each
// wave's 16x16x32 B-fragment is one contiguous 1 KB line -> coalesced
// global_load_dwordx4 straight into the MFMA operand regs. This halves the
// LDS pipe traffic (was ~192 KB/CU/iter ~ 1900 cyc -> ~96 KB ~ 1000 cyc,
// the R7 bottleneck) and moves B onto the separate TCP/vector-mem pipe.
// Block mapping ncol = bid>>6: per XCD the live B panel is 512 KB
// (L2-resident) and all 4 co-resident blocks of a CU share it (L1 hits).
// LDS now 16 KB/block; VGPR cap (256,4) kept -> 4 blocks/CU exact residency.

typedef __bf16 bf16x8  __attribute__((ext_vector_type(8)));
typedef float  f32x4   __attribute__((ext_vector_type(4)));

#define BM 128
#define BN 128
#define BK 32

__device__ __forceinline__ void async_copy16(void* lds_dst, const void* g_src) {
    // global -> LDS direct copy, 16B/lane; dest is wave-uniform base, HW
    // scatters lane i to base + i*16.
    __builtin_amdgcn_global_load_lds(
        (__attribute__((address_space(1))) void*)g_src,
        (__attribute__((address_space(3))) void*)lds_dst,
        16, 0, 0);
}

// ---------------- kernel 1: fused prep (cast X -> bf16, fold Cayley) -------
// blocks [0, castBlocks): cast X row-major (A path unchanged).
// blocks [castBlocks, ...): fold Cayley and write Wt in FRAG-MAJOR layout:
//   element (col, kk) at idx8 = ((col>>4)*K32 + (kk>>5))*4 + ((kk>>3)&3))*16
//                               + (col&15), byte addr idx8*16 + (kk&7)*2
// so that GEMM lane (quad,l16) of tile (tileN, kb) reads its 8 elems at
// one contiguous 16 B slot, and a wave's 64 lanes cover one 1 KB line.
__global__ __launch_bounds__(256) void prep_kernel(
    const float* __restrict__ x, __bf16* __restrict__ Xb, long nx,
    const float* __restrict__ W, const float* __restrict__ cayley,
    __bf16* __restrict__ Wt, int Cin, int Cout, int castBlocks)
{
    __shared__ float Cay[512];
    if ((int)blockIdx.x < castBlocks) {
        long i = ((long)blockIdx.x * 256 + threadIdx.x) * 8;
        if (i + 8 <= nx) {
            const f32x4* p = (const f32x4*)(x + i);
            f32x4 v0 = p[0];
            f32x4 v1 = p[1];
            bf16x8 o;
            o[0] = (__bf16)v0[0]; o[1] = (__bf16)v0[1];
            o[2] = (__bf16)v0[2]; o[3] = (__bf16)v0[3];
            o[4] = (__bf16)v1[0]; o[5] = (__bf16)v1[1];
            o[6] = (__bf16)v1[2]; o[7] = (__bf16)v1[3];
            *(bf16x8*)(Xb + i) = o;
        }
        return;
    }
    // ---- fold: for (col=n, i): out elems kk = i*8+k, k=0..7 (one 16 B slot)
    for (int t = threadIdx.x; t < 512; t += 256) Cay[t] = cayley[t];
    __syncthreads();

    int flat = (blockIdx.x - castBlocks) * 256 + threadIdx.x;  // n*Cin + i
    int total = Cout * 8 * Cin;
    if (flat >= total) return;
    int i = flat % Cin;
    int n = flat / Cin;
    int o = n >> 3, l = n & 7;

    const float* wrow = W + ((size_t)o * Cin + i) * 8;
    float w8[8];
    #pragma unroll
    for (int j = 0; j < 8; ++j) w8[j] = wrow[j];

    bf16x8 outv;
    #pragma unroll
    for (int k = 0; k < 8; ++k) {
        float s = 0.f;
        #pragma unroll
        for (int j = 0; j < 8; ++j) s += Cay[j * 64 + k * 8 + l] * w8[j];
        outv[k] = (__bf16)s;
    }
    const int K32 = Cin * 8 / 32;   // K/32
    // kk = i*8+k: kb = i>>2, quad = i&3, j = k
    size_t idx8 = (((size_t)(n >> 4) * K32 + (i >> 2)) * 4 + (i & 3)) * 16
                  + (n & 15);
    *(bf16x8*)(Wt + idx8 * 8) = outv;
}

// ---------------- kernel 2: bf16 GEMM, C = A * B + bias ----------------
// A   : [M][K] bf16 row-major (LDS-staged, R7 path)
// Wt2 : frag-major B (see prep)
// C   : [M][N] fp32
__global__ __launch_bounds__(256, 4) void gemm_bt_kernel(
    const __bf16* __restrict__ A,
    const __bf16* __restrict__ Wt2,
    const float*  __restrict__ bias,
    float* __restrict__ C,
    int M, int N, int K)
{
    __shared__ __align__(16) __bf16 As0[BM * BK];  // 8 KB each
    __shared__ __align__(16) __bf16 As1[BM * BK];

    const int tid  = threadIdx.x;
    const int wave = tid >> 6;
    const int lane = tid & 63;
    const int quad = lane >> 4;   // 0..3
    const int l16  = lane & 15;   // 0..15
    const int K32  = K >> 5;

    // --- block mapping: ncol-major groups. Group g = 64 consecutive bids all
    // share ncol=g -> per XCD the live B panel is 512 KB (L2-resident) and
    // the 4 co-resident blocks of a CU share it exactly (L1 hits). A bands
    // re-read across groups are served by L3 (Xb = 32 MB << 256 MB).
    const int bid   = blockIdx.x;     // 0..1023
    const int band  = bid & 63;       // 0..63
    const int ncol  = bid >> 6;       // 0..15
    const int mBase = band * BM;
    const int nBase = ncol * BN;

    // --- A staging: 1 KB chunk = 16 rows of 64 B; 8 chunks per buffer;
    // wave w loads chunks 2w, 2w+1. XOR swizzle on source group.
    const int srow = lane >> 2;                        // 0..15 row in chunk
    const int sgrp = (lane & 3) ^ ((srow >> 1) & 3);   // swizzled 16B-group

    const __bf16* gA0 = A + (size_t)(mBase + (2 * wave + 0) * 16 + srow) * K + sgrp * 8;
    const __bf16* gA1 = A + (size_t)(mBase + (2 * wave + 1) * 16 + srow) * K + sgrp * 8;
    const int cOff0 = (2 * wave + 0) * 512;   // 512 bf16 = 1 KB chunk
    const int cOff1 = (2 * wave + 1) * 512;

    // --- compute: wave quadrant (64x64), 4x4 grid of 16x16x32 MFMA tiles
    const int wm = (wave >> 1) * 64;
    const int wn = (wave & 1) * 64;
    const int offq = (quad ^ ((l16 >> 1) & 3)) * 8;  // swizzled A frag offset
    const int rowA = (wm + l16) * BK;

    // --- B direct-load pointers: frag-major; wave's nt-frag = contiguous 1 KB
    const int tileN = (nBase + wn) >> 4;
    const __bf16* pB[4];
    #pragma unroll
    for (int nt = 0; nt < 4; ++nt)
        pB[nt] = Wt2 + ((((size_t)(tileN + nt) * K32) * 4 + quad) * 16 + l16) * 8;
    // per-iter advance: kb+1 -> +4*16*8 = 512 elements

    f32x4 acc[4][4] = {};

#define PREFETCH_A(BUFA, KOFF)                           \
    do {                                                 \
        async_copy16(&BUFA[cOff0], gA0 + (KOFF));        \
        async_copy16(&BUFA[cOff1], gA1 + (KOFF));        \
    } while (0)

#define COMPUTE(BUFA, KB)                                                 \
    do {                                                                  \
        bf16x8 bfr[4];                                                    \
        _Pragma("unroll")                                                 \
        for (int nt = 0; nt < 4; ++nt)                                    \
            bfr[nt] = *(const bf16x8*)(pB[nt] + (size_t)(KB) * 512);      \
        const __bf16* fA = &BUFA[rowA] + offq;                            \
        bf16x8 af[4];                                                     \
        _Pragma("unroll")                                                 \
        for (int mt = 0; mt < 4; ++mt)                                    \
            af[mt] = *(const bf16x8*)(fA + mt * 16 * BK);                 \
        _Pragma("unroll")                                                 \
        for (int nt = 0; nt < 4; ++nt)                                    \
            _Pragma("unroll")                                             \
            for (int mt = 0; mt < 4; ++mt)                                \
                acc[mt][nt] = __builtin_amdgcn_mfma_f32_16x16x32_bf16(    \
                    af[mt], bfr[nt], acc[mt][nt], 0, 0, 0);               \
    } while (0)

    // --- prologue: stage A(0)
    PREFETCH_A(As0, 0);

    // --- main loop: phase = barrier; prefetch next A; load this iter's B
    // direct to regs (L1/L2-hot, latency hidden by 16 waves/CU); compute.
    int k0 = 0;
    int kb = 0;
    for (; k0 < K - 2 * BK; k0 += 2 * BK, kb += 2) {
        __syncthreads();
        PREFETCH_A(As1, k0 + BK);
        COMPUTE(As0, kb);

        __syncthreads();
        PREFETCH_A(As0, k0 + 2 * BK);
        COMPUTE(As1, kb + 1);
    }

    // --- tail pair
    __syncthreads();
    PREFETCH_A(As1, k0 + BK);
    COMPUTE(As0, kb);

    __syncthreads();
    COMPUTE(As1, kb + 1);

#undef PREFETCH_A
#undef COMPUTE

    // --- epilogue: C/D layout col = lane&15, row = quad*4 + reg
    float bv[4];
    #pragma unroll
    for (int nt = 0; nt < 4; ++nt)
        bv[nt] = bias[nBase + wn + nt * 16 + l16];

    #pragma unroll
    for (int mt = 0; mt < 4; ++mt) {
        #pragma unroll
        for (int nt = 0; nt < 4; ++nt) {
            const int col = nBase + wn + nt * 16 + l16;
            #pragma unroll
            for (int r = 0; r < 4; ++r) {
                const int row = mBase + wm + mt * 16 + quad * 4 + r;
                C[(size_t)row * N + col] = acc[mt][nt][r] + bv[nt];
            }
        }
    }
}

extern "C" void kernel_launch(void* const* d_in, const int* in_sizes, int n_in,
                              void* d_out, int out_size, void* d_ws, size_t ws_size,
                              hipStream_t stream) {
    const float* x      = (const float*)d_in[0];  // [B][Cin][8]
    const float* weight = (const float*)d_in[1];  // [Cout][Cin][8]
    const float* bias   = (const float*)d_in[2];  // [Cout][8]
    const float* cayley = (const float*)d_in[3];  // [8][8][8]
    float* out = (float*)d_out;                   // [B][Cout][8]

    const int Cout = in_sizes[2] / 8;
    const int Cin  = in_sizes[1] / (Cout * 8);
    const int Bm   = in_sizes[0] / (Cin * 8);
    const int M = Bm;          // 8192
    const int N = Cout * 8;    // 2048
    const int K = Cin * 8;     // 2048

    __bf16* Xb = (__bf16*)d_ws;                               // M*K bf16 = 32 MB
    __bf16* Wt = (__bf16*)((char*)d_ws + (size_t)M * K * 2);  // N*K bf16 = 8 MB

    // 1) fused prep: cast X + fold Cayley (frag-major Wt), one dispatch
    long nx = (long)M * K;
    int castBlocks = (int)(nx / 8 / 256);               // nx divisible by 2048
    int foldBlocks = (N * Cin + 255) / 256;
    prep_kernel<<<castBlocks + foldBlocks, 256, 0, stream>>>(
        x, Xb, nx, weight, cayley, Wt, Cin, Cout, castBlocks);

    // 2) GEMM
    int grid = (M / BM) * (N / BN);   // 64 * 16 = 1024
    gemm_bt_kernel<<<grid, 256, 0, stream>>>(Xb, Wt, bias, out, M, N, K);
}

// Round 9
// 202.995 us; speedup vs baseline: 1.0074x; 1.0074x over previous
//
#include <hip/hip_runtime.h>
#include <stdint.h>
#include <stddef.h>

// CliffordLinear as one bf16 GEMM:
//   out[b, o*8+l] = sum_{i,k} X[b, i*8+k] * Wt[o*8+l, i*8+k] + bias[o*8+l]
//   Wt[(o,l),(i,k)] = sum_j cayley[j,k,l] * W[o,i,j]
// M=8192, N=2048, K=2048. bf16 MFMA, fp32 accumulate.
//
// R9 = R8 hybrid (A via LDS dbuf, B direct-to-reg from frag-major Wt) with
// two ordering fixes:
//  (a) GEMM phase issues B global_loads BEFORE the A global_load_lds
//      prefetch. vmcnt retires in issue order, so the B-use wait becomes
//      vmcnt(2) -- A's 2 staging loads stay in flight across the whole
//      compute phase. R8 issued A first, making the B wait an effective
//      vmcnt(0) that drained the A prefetch every phase (R4-style
//      serialization, GEMM 89->94 regression).
//  (b) prep fold threads re-indexed by OUTPUT slot: thread t writes
//      Wt + 8t (coalesced 16 B/lane, 1 KB/wave); R8's (n,i) indexing
//      scattered stores at 256 B stride (+11 us on prep).

typedef __bf16 bf16x8  __attribute__((ext_vector_type(8)));
typedef float  f32x4   __attribute__((ext_vector_type(4)));

#define BM 128
#define BN 128
#define BK 32

__device__ __forceinline__ void async_copy16(void* lds_dst, const void* g_src) {
    // global -> LDS direct copy, 16B/lane; dest is wave-uniform base, HW
    // scatters lane i to base + i*16.
    __builtin_amdgcn_global_load_lds(
        (__attribute__((address_space(1))) void*)g_src,
        (__attribute__((address_space(3))) void*)lds_dst,
        16, 0, 0);
}

// ---------------- kernel 1: fused prep (cast X -> bf16, fold Cayley) -------
// blocks [0, castBlocks): cast X row-major (A path).
// blocks [castBlocks, ...): fold Cayley -> frag-major Wt, coalesced writes.
// Frag-major slot t (16 B = 8 bf16, k-contiguous):
//   t = ((tileN * K32 + kb) * 4 + quad) * 16 + col_lo
//   holds B[n = tileN*16 + col_lo][kk = (kb*4 + quad)*8 .. +7]
// GEMM lane (quad,l16) of tile (tileN,kb) reads slot -> one bf16x8.
__global__ __launch_bounds__(256) void prep_kernel(
    const float* __restrict__ x, __bf16* __restrict__ Xb, long nx,
    const float* __restrict__ W, const float* __restrict__ cayley,
    __bf16* __restrict__ Wt, int Cin, int Cout, int castBlocks)
{
    __shared__ float Cay[512];
    if ((int)blockIdx.x < castBlocks) {
        long i = ((long)blockIdx.x * 256 + threadIdx.x) * 8;
        if (i + 8 <= nx) {
            const f32x4* p = (const f32x4*)(x + i);
            f32x4 v0 = p[0];
            f32x4 v1 = p[1];
            bf16x8 o;
            o[0] = (__bf16)v0[0]; o[1] = (__bf16)v0[1];
            o[2] = (__bf16)v0[2]; o[3] = (__bf16)v0[3];
            o[4] = (__bf16)v1[0]; o[5] = (__bf16)v1[1];
            o[6] = (__bf16)v1[2]; o[7] = (__bf16)v1[3];
            *(bf16x8*)(Xb + i) = o;
        }
        return;
    }
    for (int t = threadIdx.x; t < 512; t += 256) Cay[t] = cayley[t];
    __syncthreads();

    int t = (blockIdx.x - castBlocks) * 256 + threadIdx.x;  // output slot id
    int total = Cout * 8 * Cin;   // == N/16 * K32 * 4 * 16
    if (t >= total) return;

    const int K32 = Cin * 8 / 32;
    const int col_lo = t & 15;
    const int quad_i = (t >> 4) & 3;
    const int rest   = t >> 6;
    const int kb     = rest % K32;
    const int tileN  = rest / K32;

    const int n = (tileN << 4) | col_lo;   // output column
    const int i = kb * 4 + quad_i;         // input channel
    const int o = n >> 3, l = n & 7;

    const float* wrow = W + ((size_t)o * Cin + i) * 8;
    float w8[8];
    #pragma unroll
    for (int j = 0; j < 8; ++j) w8[j] = wrow[j];

    bf16x8 outv;
    #pragma unroll
    for (int k = 0; k < 8; ++k) {
        float s = 0.f;
        #pragma unroll
        for (int j = 0; j < 8; ++j) s += Cay[j * 64 + k * 8 + l] * w8[j];
        outv[k] = (__bf16)s;
    }
    *(bf16x8*)(Wt + (size_t)t * 8) = outv;   // coalesced: 16 B/lane contiguous
}

// ---------------- kernel 2: bf16 GEMM, C = A * B + bias ----------------
// A   : [M][K] bf16 row-major (LDS-staged, R7 path, XOR swizzle, 0 conflicts)
// Wt2 : frag-major B (see prep) -- direct global->reg, no LDS
// C   : [M][N] fp32
__global__ __launch_bounds__(256, 4) void gemm_bt_kernel(
    const __bf16* __restrict__ A,
    const __bf16* __restrict__ Wt2,
    const float*  __restrict__ bias,
    float* __restrict__ C,
    int M, int N, int K)
{
    __shared__ __align__(16) __bf16 As0[BM * BK];  // 8 KB each
    __shared__ __align__(16) __bf16 As1[BM * BK];

    const int tid  = threadIdx.x;
    const int wave = tid >> 6;
    const int lane = tid & 63;
    const int quad = lane >> 4;   // 0..3
    const int l16  = lane & 15;   // 0..15
    const int K32  = K >> 5;

    // --- block mapping: ncol-major groups -> per-XCD B panel 512 KB
    // (L2-resident), 4 co-resident blocks/CU share it (L1 hits). R8 measured
    // FETCH 79->53 MB with this mapping.
    const int bid   = blockIdx.x;     // 0..1023
    const int band  = bid & 63;       // 0..63
    const int ncol  = bid >> 6;       // 0..15
    const int mBase = band * BM;
    const int nBase = ncol * BN;

    // --- A staging: 1 KB chunk = 16 rows of 64 B; 8 chunks per buffer;
    // wave w loads chunks 2w, 2w+1. XOR swizzle on source group.
    const int srow = lane >> 2;                        // 0..15 row in chunk
    const int sgrp = (lane & 3) ^ ((srow >> 1) & 3);   // swizzled 16B-group

    const __bf16* gA0 = A + (size_t)(mBase + (2 * wave + 0) * 16 + srow) * K + sgrp * 8;
    const __bf16* gA1 = A + (size_t)(mBase + (2 * wave + 1) * 16 + srow) * K + sgrp * 8;
    const int cOff0 = (2 * wave + 0) * 512;   // 512 bf16 = 1 KB chunk
    const int cOff1 = (2 * wave + 1) * 512;

    // --- compute: wave quadrant (64x64), 4x4 grid of 16x16x32 MFMA tiles
    const int wm = (wave >> 1) * 64;
    const int wn = (wave & 1) * 64;
    const int offq = (quad ^ ((l16 >> 1) & 3)) * 8;  // swizzled A frag offset
    const int rowA = (wm + l16) * BK;

    // --- B direct-load pointers: frag-major; wave's nt-frag = contiguous 1 KB
    const int tileN = (nBase + wn) >> 4;
    const __bf16* pB[4];
    #pragma unroll
    for (int nt = 0; nt < 4; ++nt)
        pB[nt] = Wt2 + ((((size_t)(tileN + nt) * K32) * 4 + quad) * 16 + l16) * 8;
    // per-iter advance: kb+1 -> +512 elements

    f32x4 acc[4][4] = {};

    // Phase: barrier; B loads FIRST (so their wait is vmcnt(2), leaving the
    // A prefetch in flight); A prefetch; A ds_reads; MFMA.
#define PHASE(BUFA, KB, PFBUF, PFOFF, DOPF)                               \
    do {                                                                  \
        __syncthreads();                                                  \
        bf16x8 bfr[4];                                                    \
        _Pragma("unroll")                                                 \
        for (int nt = 0; nt < 4; ++nt)                                    \
            bfr[nt] = *(const bf16x8*)(pB[nt] + (size_t)(KB) * 512);      \
        if (DOPF) {                                                       \
            async_copy16(&PFBUF[cOff0], gA0 + (PFOFF));                   \
            async_copy16(&PFBUF[cOff1], gA1 + (PFOFF));                   \
        }                                                                 \
        const __bf16* fA = &BUFA[rowA] + offq;                            \
        bf16x8 af[4];                                                     \
        _Pragma("unroll")                                                 \
        for (int mt = 0; mt < 4; ++mt)                                    \
            af[mt] = *(const bf16x8*)(fA + mt * 16 * BK);                 \
        _Pragma("unroll")                                                 \
        for (int nt = 0; nt < 4; ++nt)                                    \
            _Pragma("unroll")                                             \
            for (int mt = 0; mt < 4; ++mt)                                \
                acc[mt][nt] = __builtin_amdgcn_mfma_f32_16x16x32_bf16(    \
                    af[mt], bfr[nt], acc[mt][nt], 0, 0, 0);               \
    } while (0)

    // --- prologue: stage A(0)
    async_copy16(&As0[cOff0], gA0);
    async_copy16(&As0[cOff1], gA1);

    int k0 = 0;
    int kb = 0;
    for (; k0 < K - 2 * BK; k0 += 2 * BK, kb += 2) {
        PHASE(As0, kb,     As1, k0 + BK,     true);
        PHASE(As1, kb + 1, As0, k0 + 2 * BK, true);
    }
    // tail pair
    PHASE(As0, kb,     As1, k0 + BK, true);
    PHASE(As1, kb + 1, As0, 0,       false);

#undef PHASE

    // --- epilogue: C/D layout col = lane&15, row = quad*4 + reg
    float bv[4];
    #pragma unroll
    for (int nt = 0; nt < 4; ++nt)
        bv[nt] = bias[nBase + wn + nt * 16 + l16];

    #pragma unroll
    for (int mt = 0; mt < 4; ++mt) {
        #pragma unroll
        for (int nt = 0; nt < 4; ++nt) {
            const int col = nBase + wn + nt * 16 + l16;
            #pragma unroll
            for (int r = 0; r < 4; ++r) {
                const int row = mBase + wm + mt * 16 + quad * 4 + r;
                C[(size_t)row * N + col] = acc[mt][nt][r] + bv[nt];
            }
        }
    }
}

extern "C" void kernel_launch(void* const* d_in, const int* in_sizes, int n_in,
                              void* d_out, int out_size, void* d_ws, size_t ws_size,
                              hipStream_t stream) {
    const float* x      = (const float*)d_in[0];  // [B][Cin][8]
    const float* weight = (const float*)d_in[1];  // [Cout][Cin][8]
    const float* bias   = (const float*)d_in[2];  // [Cout][8]
    const float* cayley = (const float*)d_in[3];  // [8][8][8]
    float* out = (float*)d_out;                   // [B][Cout][8]

    const int Cout = in_sizes[2] / 8;
    const int Cin  = in_sizes[1] / (Cout * 8);
    const int Bm   = in_sizes[0] / (Cin * 8);
    const int M = Bm;          // 8192
    const int N = Cout * 8;    // 2048
    const int K = Cin * 8;     // 2048

    __bf16* Xb = (__bf16*)d_ws;                               // M*K bf16 = 32 MB
    __bf16* Wt = (__bf16*)((char*)d_ws + (size_t)M * K * 2);  // N*K bf16 = 8 MB

    // 1) fused prep: cast X + fold Cayley (frag-major Wt), one dispatch
    long nx = (long)M * K;
    int castBlocks = (int)(nx / 8 / 256);               // nx divisible by 2048
    int foldBlocks = (N * Cin + 255) / 256;
    prep_kernel<<<castBlocks + foldBlocks, 256, 0, stream>>>(
        x, Xb, nx, weight, cayley, Wt, Cin, Cout, castBlocks);

    // 2) GEMM
    int grid = (M / BM) * (N / BN);   // 64 * 16 = 1024
    gemm_bt_kernel<<<grid, 256, 0, stream>>>(Xb, Wt, bias, out, M, N, K);
}